// Round 3
// baseline (5350.541 us; speedup 1.0000x reference)
//
#include <hip/hip_runtime.h>
#include <cmath>

#define IN_CH 128
#define NROUNDS 6

// Monotone descending key: smaller key == higher norm; ties -> smaller edge idx
// (matches stable argsort of -norm).
__device__ __forceinline__ unsigned long long make_key(float norm, int e) {
    unsigned int b = __float_as_uint(norm);
    unsigned int asc = (b & 0x80000000u) ? ~b : (b | 0x80000000u); // monotone-increasing map
    unsigned int desc = ~asc;
    return (((unsigned long long)desc) << 32) | (unsigned int)e;
}

__global__ void init_kernel(unsigned int* node_max, double* denom, int* matched,
                            unsigned long long* best0, unsigned long long* best1,
                            int* cluster, int* partner, float* s_rep, int* counters, int N) {
    int i = blockIdx.x * blockDim.x + threadIdx.x;
    if (i < N) {
        node_max[i] = 0u;          // bits of +0.0f; any positive score has bits > 0
        denom[i]    = 0.0;
        matched[i]  = 0;
        best0[i]    = ~0ULL;
        best1[i]    = ~0ULL;
        cluster[i]  = i;
        partner[i]  = i;
        s_rep[i]    = 1.0f;
    }
    if (i < 64) counters[i] = 0;
}

// One wave per node: p[n] = dot(x[n], w_src), q[n] = dot(x[n], w_dst), double accum.
__global__ void proj_kernel(const float* __restrict__ x, const float* __restrict__ w_src,
                            const float* __restrict__ w_dst, float* __restrict__ p,
                            float* __restrict__ q, int N) {
    int wave = (blockIdx.x * blockDim.x + threadIdx.x) >> 6;
    int lane = threadIdx.x & 63;
    if (wave >= N) return;
    float2 xv = ((const float2*)(x + (size_t)wave * IN_CH))[lane];
    float2 ws = ((const float2*)w_src)[lane];
    float2 wd = ((const float2*)w_dst)[lane];
    double ap = (double)xv.x * (double)ws.x + (double)xv.y * (double)ws.y;
    double aq = (double)xv.x * (double)wd.x + (double)xv.y * (double)wd.y;
    #pragma unroll
    for (int off = 32; off > 0; off >>= 1) {
        ap += __shfl_down(ap, off);
        aq += __shfl_down(aq, off);
    }
    if (lane == 0) { p[wave] = (float)ap; q[wave] = (float)aq; }
}

__global__ void score_kernel(const int* __restrict__ row, const int* __restrict__ col,
                             const float* __restrict__ p, const float* __restrict__ q,
                             const float* __restrict__ bptr, float* __restrict__ score,
                             unsigned int* __restrict__ node_max, int E) {
    int e = blockIdx.x * blockDim.x + threadIdx.x;
    if (e >= E) return;
    float s = p[row[e]] + q[col[e]] + bptr[0];
    score[e] = s;
    if (s > 0.0f) atomicMax(&node_max[row[e]], __float_as_uint(s));
}

__global__ void exp_kernel(const int* __restrict__ row, const float* __restrict__ score,
                           const unsigned int* __restrict__ node_max, float* __restrict__ norm,
                           double* __restrict__ denom, int E) {
    int e = blockIdx.x * blockDim.x + threadIdx.x;
    if (e >= E) return;
    int u = row[e];
    unsigned int mb = node_max[u];
    float s = score[e];
    float ev = 0.0f;
    if (mb != 0u && s > 0.0f) {
        float m = __uint_as_float(mb);
        ev = (float)exp((double)(s - m));   // double exp ~correctly rounded
        atomicAdd(&denom[u], (double)ev);   // order-independent (double accum)
    }
    norm[e] = ev;
}

__global__ void norm_kernel(const int* __restrict__ row, const float* __restrict__ score,
                            const unsigned int* __restrict__ node_max,
                            const double* __restrict__ denom, float* __restrict__ norm,
                            unsigned long long* __restrict__ key, int E) {
    int e = blockIdx.x * blockDim.x + threadIdx.x;
    if (e >= E) return;
    int u = row[e];
    unsigned int mb = node_max[u];
    float nv;
    if (mb != 0u) {
        float s = score[e];
        if (s > 0.0f) {
            float d = (float)denom[u];
            nv = norm[e] / d + 0.5f;        // exact f32 div + add, same as ref
        } else {
            nv = 0.0f;
        }
    } else {
        nv = score[e];                       // raw score for rows with no positive edge
    }
    norm[e] = nv;
    key[e] = make_key(nv, e);
}

// Wave-aggregated list append.
__device__ __forceinline__ void append(bool live, int e, int* list, int* cnt) {
    unsigned long long mask = __ballot(live);
    if (mask == 0ULL) return;
    int lane = threadIdx.x & 63;
    int leader = __ffsll(mask) - 1;
    int base;
    if (lane == leader) base = atomicAdd(cnt, __popcll(mask));
    base = __shfl(base, leader);
    if (live) list[base + __popcll(mask & ((1ULL << lane) - 1))] = e;
}

__global__ void scatter0_kernel(const int* __restrict__ row, const int* __restrict__ col,
                                const unsigned long long* __restrict__ key,
                                unsigned long long* __restrict__ best,
                                int* __restrict__ list, int* __restrict__ cnt, int E) {
    int e = blockIdx.x * blockDim.x + threadIdx.x;
    bool live = false;
    if (e < E) {
        int u = row[e], v = col[e];
        if (u != v) {
            live = true;
            unsigned long long k = key[e];
            atomicMin(&best[u], k);
            atomicMin(&best[v], k);
        }
    }
    append(live, e, list, cnt);
}

// Select winners (unique mutual-min of pre-scattered bcur); reset bnext for the
// following scatter dispatch. Dispatch boundaries give full coherence.
__global__ void select_kernel(const int* __restrict__ row, const int* __restrict__ col,
                              const unsigned long long* __restrict__ key,
                              const float* __restrict__ norm, int* __restrict__ matched,
                              const unsigned long long* __restrict__ bcur,
                              unsigned long long* __restrict__ bnext,
                              const int* __restrict__ list, const int* __restrict__ cnt_in,
                              int* __restrict__ cluster, int* __restrict__ partner,
                              float* __restrict__ s_rep, int N) {
    int n = *cnt_in;
    if (n == 0) return;
    int gtid = blockIdx.x * blockDim.x + threadIdx.x;
    int gsz  = gridDim.x * blockDim.x;
    for (int i = gtid; i < n; i += gsz) {
        int e = list[i];
        int u = row[e], v = col[e];
        if (matched[u] | matched[v]) continue;   // racy but only skips provably-dead edges
        unsigned long long k = key[e];
        if (bcur[u] == k && bcur[v] == k) {      // unique min at both ends -> greedy winner
            matched[u] = 1; matched[v] = 1;
            cluster[v] = u; partner[u] = v; s_rep[u] = norm[e];
        }
    }
    for (int i = gtid; i < N; i += gsz) bnext[i] = ~0ULL;
}

// Coherent matched[] now: prune dead edges, compact survivors, scatter into bnext.
__global__ void scatter_kernel(const int* __restrict__ row, const int* __restrict__ col,
                               const unsigned long long* __restrict__ key,
                               const int* __restrict__ matched,
                               unsigned long long* __restrict__ bnext,
                               const int* __restrict__ list_in, const int* __restrict__ cnt_in,
                               int* __restrict__ list_out, int* __restrict__ cnt_out) {
    int n = *cnt_in;
    if (n == 0) return;
    int gtid = blockIdx.x * blockDim.x + threadIdx.x;
    int gsz  = gridDim.x * blockDim.x;
    for (int i = gtid; i < n; i += gsz) {
        int e = list_in[i];
        int u = row[e], v = col[e];
        bool live = !(matched[u] | matched[v]);
        if (live) {
            unsigned long long k = key[e];
            atomicMin(&bnext[u], k);
            atomicMin(&bnext[v], k);
        }
        append(live, e, list_out, cnt_out);
    }
}

#define AL(p)    __hip_atomic_load((p), __ATOMIC_RELAXED, __HIP_MEMORY_SCOPE_AGENT)
#define AS(p, x) __hip_atomic_store((p), (x), __ATOMIC_RELAXED, __HIP_MEMORY_SCOPE_AGENT)

// Single-block finisher: exact locally-dominant rounds with no device-wide syncs.
// Entry state: bb pre-scattered over the live edges in listA (count *cnt_in).
__global__ void __launch_bounds__(1024) tail_kernel(
        const int* __restrict__ row, const int* __restrict__ col,
        const unsigned long long* __restrict__ key, const float* __restrict__ norm,
        int* __restrict__ matched, unsigned long long* __restrict__ bb,
        int* __restrict__ listA, int* __restrict__ listB, const int* __restrict__ cnt_in,
        int* __restrict__ cluster, int* __restrict__ partner, float* __restrict__ s_rep) {
    int n = *cnt_in;
    int* lin = listA;
    int* lout = listB;
    __shared__ int scnt;
    for (int iter = 0; iter < 20000 && n > 0; ++iter) {
        if (threadIdx.x == 0) scnt = 0;
        __syncthreads();
        // Phase B: select winners from pre-scattered bb; compact survivors.
        for (int i = threadIdx.x; i < n; i += blockDim.x) {
            int e = lin[i];
            int u = row[e], v = col[e];
            if (AL(&matched[u]) | AL(&matched[v])) continue;
            unsigned long long k = key[e];
            if (AL(&bb[u]) == k && AL(&bb[v]) == k) {
                AS(&matched[u], 1); AS(&matched[v], 1);
                cluster[v] = u; partner[u] = v; s_rep[u] = norm[e];
            } else {
                int pos = atomicAdd(&scnt, 1);
                lout[pos] = e;
            }
        }
        __syncthreads();
        __threadfence();
        // Phase C: reset bb at all endpoints touched (lin superset of lout).
        for (int i = threadIdx.x; i < n; i += blockDim.x) {
            int e = lin[i];
            AS(&bb[row[e]], ~0ULL);
            AS(&bb[col[e]], ~0ULL);
        }
        __syncthreads();
        __threadfence();
        int nn = scnt;
        // Phase A: re-scatter survivors (matched now visible; prunes stale entries).
        for (int i = threadIdx.x; i < nn; i += blockDim.x) {
            int e = lout[i];
            int u = row[e], v = col[e];
            if (AL(&matched[u]) | AL(&matched[v])) continue;
            unsigned long long k = key[e];
            atomicMin(&bb[u], k);
            atomicMin(&bb[v], k);
        }
        __syncthreads();
        __threadfence();
        n = nn;
        int* t = lin; lin = lout; lout = t;
    }
}

__global__ void newx_kernel(const float* __restrict__ x, const int* __restrict__ cluster,
                            const int* __restrict__ matched, const int* __restrict__ partner,
                            const float* __restrict__ s_rep, float* __restrict__ out,
                            float* __restrict__ out_cluster, float* __restrict__ out_isrep,
                            int N) {
    int t = blockIdx.x * blockDim.x + threadIdx.x;
    if (t >= N * (IN_CH / 4)) return;
    int n = t >> 5;            // IN_CH/4 == 32 float4 per node
    int c = (t & 31) * 4;
    int cl = cluster[n];
    if ((t & 31) == 0) {
        out_cluster[n] = (float)cl;
        out_isrep[n]   = (cl == n) ? 1.0f : 0.0f;
    }
    float4 o;
    if (cl != n) {
        o = make_float4(0.f, 0.f, 0.f, 0.f);              // merged-away node row
    } else if (matched[n]) {
        int v = partner[n];
        float s = s_rep[n];
        float4 xu = *(const float4*)(x + (size_t)n * IN_CH + c);
        float4 xv = *(const float4*)(x + (size_t)v * IN_CH + c);
        o.x = (xu.x + xv.x) * s + xv.x;
        o.y = (xu.y + xv.y) * s + xv.y;
        o.z = (xu.z + xv.z) * s + xv.z;
        o.w = (xu.w + xv.w) * s + xv.w;
    } else {
        o = *(const float4*)(x + (size_t)n * IN_CH + c);  // untouched node
    }
    ((float4*)out)[t] = o;
}

__global__ void edges_kernel(const int* __restrict__ row, const int* __restrict__ col,
                             const float* __restrict__ w, const int* __restrict__ cluster,
                             float* __restrict__ out_nrow, float* __restrict__ out_ncol,
                             float* __restrict__ out_valid, float* __restrict__ out_w, int E) {
    int e = blockIdx.x * blockDim.x + threadIdx.x;
    if (e >= E) return;
    int nr = cluster[row[e]];
    int nc = cluster[col[e]];
    out_nrow[e]  = (float)nr;
    out_ncol[e]  = (float)nc;
    out_valid[e] = (nr != nc) ? 1.0f : 0.0f;
    out_w[e]     = w[e];
}

extern "C" void kernel_launch(void* const* d_in, const int* in_sizes, int n_in_args,
                              void* d_out, int out_size, void* d_ws, size_t ws_size,
                              hipStream_t stream) {
    const float* x     = (const float*)d_in[0];
    const float* w_src = (const float*)d_in[1];
    const float* w_dst = (const float*)d_in[2];
    const float* bptr  = (const float*)d_in[3];
    const int*   ei    = (const int*)d_in[4];
    const float* ew    = (const float*)d_in[5];
    const int N = in_sizes[0] / IN_CH;
    const int E = in_sizes[5];
    const int* row = ei;
    const int* col = ei + E;

    char* ws = (char*)d_ws;
    size_t off = 0;
    auto alloc = [&](size_t bytes) -> void* {
        off = (off + 255) & ~(size_t)255;
        void* ptr = ws + off;
        off += bytes;
        return ptr;
    };
    float*              score    = (float*)alloc((size_t)E * 4);
    float*              norm     = (float*)alloc((size_t)E * 4);
    unsigned long long* key      = (unsigned long long*)alloc((size_t)E * 8);
    int*                list0    = (int*)alloc((size_t)E * 4);
    int*                list1    = (int*)alloc((size_t)E * 4);
    unsigned int*       node_max = (unsigned int*)alloc((size_t)N * 4);
    double*             denom    = (double*)alloc((size_t)N * 8);
    int*                matched  = (int*)alloc((size_t)N * 4);
    unsigned long long* best0    = (unsigned long long*)alloc((size_t)N * 8);
    unsigned long long* best1    = (unsigned long long*)alloc((size_t)N * 8);
    int*                cluster  = (int*)alloc((size_t)N * 4);
    int*                partner  = (int*)alloc((size_t)N * 4);
    float*              s_rep    = (float*)alloc((size_t)N * 4);
    float*              pbuf     = (float*)alloc((size_t)N * 4);
    float*              qbuf     = (float*)alloc((size_t)N * 4);
    int*                counters = (int*)alloc(64 * 4);

    // Output layout: new_x[N*128] | cluster[N] | is_rep[N] | new_row[E] | new_col[E] | edge_valid[E] | edge_weight[E]
    float* out       = (float*)d_out;
    float* o_newx    = out;
    float* o_cluster = out + (size_t)N * IN_CH;
    float* o_isrep   = o_cluster + N;
    float* o_nrow    = o_isrep + N;
    float* o_ncol    = o_nrow + E;
    float* o_valid   = o_ncol + E;
    float* o_w       = o_valid + E;

    unsigned long long* W[2] = {best0, best1};
    int* L[2] = {list0, list1};

    const int T = 256;
    hipLaunchKernelGGL(init_kernel, dim3((N + T - 1) / T), dim3(T), 0, stream,
                       node_max, denom, matched, best0, best1, cluster, partner, s_rep,
                       counters, N);
    hipLaunchKernelGGL(proj_kernel, dim3((N * 64 + T - 1) / T), dim3(T), 0, stream,
                       x, w_src, w_dst, pbuf, qbuf, N);
    hipLaunchKernelGGL(score_kernel, dim3((E + T - 1) / T), dim3(T), 0, stream,
                       row, col, pbuf, qbuf, bptr, score, node_max, E);
    hipLaunchKernelGGL(exp_kernel, dim3((E + T - 1) / T), dim3(T), 0, stream,
                       row, score, node_max, norm, denom, E);
    hipLaunchKernelGGL(norm_kernel, dim3((E + T - 1) / T), dim3(T), 0, stream,
                       row, score, node_max, denom, norm, key, E);

    // Matching: dispatch boundaries serve as coherent device-wide barriers.
    hipLaunchKernelGGL(scatter0_kernel, dim3((E + T - 1) / T), dim3(T), 0, stream,
                       row, col, key, W[1], L[0], &counters[1], E);
    const dim3 rgrid(512), rblk(256);
    for (int r = 1; r <= NROUNDS; ++r) {
        hipLaunchKernelGGL(select_kernel, rgrid, rblk, 0, stream,
                           row, col, key, norm, matched, W[r & 1], W[1 - (r & 1)],
                           L[(r - 1) & 1], &counters[r], cluster, partner, s_rep, N);
        hipLaunchKernelGGL(scatter_kernel, rgrid, rblk, 0, stream,
                           row, col, key, matched, W[1 - (r & 1)],
                           L[(r - 1) & 1], &counters[r], L[r & 1], &counters[r + 1]);
    }
    hipLaunchKernelGGL(tail_kernel, dim3(1), dim3(1024), 0, stream,
                       row, col, key, norm, matched, W[1 - (NROUNDS & 1)],
                       L[NROUNDS & 1], L[1 - (NROUNDS & 1)], &counters[NROUNDS + 1],
                       cluster, partner, s_rep);

    hipLaunchKernelGGL(newx_kernel, dim3((N * 32 + T - 1) / T), dim3(T), 0, stream,
                       x, cluster, matched, partner, s_rep, o_newx, o_cluster, o_isrep, N);
    hipLaunchKernelGGL(edges_kernel, dim3((E + T - 1) / T), dim3(T), 0, stream,
                       row, col, ew, cluster, o_nrow, o_ncol, o_valid, o_w, E);
    (void)score; (void)ws_size; (void)out_size; (void)n_in_args;
}

// Round 4
// 733.917 us; speedup vs baseline: 7.2904x; 7.2904x over previous
//
#include <hip/hip_runtime.h>
#include <cmath>

#define IN_CH 128
#define AL(p) __hip_atomic_load((p), __ATOMIC_RELAXED, __HIP_MEMORY_SCOPE_AGENT)

// Monotone descending key: smaller key == higher norm; ties -> smaller edge idx
// (matches stable argsort of -norm). All keys distinct.
__device__ __forceinline__ unsigned long long make_key(float norm, int e) {
    unsigned int b = __float_as_uint(norm);
    unsigned int asc = (b & 0x80000000u) ? ~b : (b | 0x80000000u); // monotone-increasing map
    unsigned int desc = ~asc;
    return (((unsigned long long)desc) << 32) | (unsigned int)e;
}

__global__ void init_kernel(unsigned int* node_max, double* denom, unsigned long long* ws,
                            int* deg, int* cluster, int* partner, float* s_rep, int N) {
    int i = blockIdx.x * blockDim.x + threadIdx.x;
    if (i >= N) return;
    node_max[i] = 0u;          // bits of +0.0f; any positive score has bits > 0
    denom[i]    = 0.0;
    ws[i]       = ~0ULL;
    deg[i]      = 0;
    cluster[i]  = i;
    partner[i]  = i;
    s_rep[i]    = 1.0f;
}

// One wave per node: p[n] = dot(x[n], w_src), q[n] = dot(x[n], w_dst), double accum.
__global__ void proj_kernel(const float* __restrict__ x, const float* __restrict__ w_src,
                            const float* __restrict__ w_dst, float* __restrict__ p,
                            float* __restrict__ q, int N) {
    int wave = (blockIdx.x * blockDim.x + threadIdx.x) >> 6;
    int lane = threadIdx.x & 63;
    if (wave >= N) return;
    float2 xv = ((const float2*)(x + (size_t)wave * IN_CH))[lane];
    float2 ws = ((const float2*)w_src)[lane];
    float2 wd = ((const float2*)w_dst)[lane];
    double ap = (double)xv.x * (double)ws.x + (double)xv.y * (double)ws.y;
    double aq = (double)xv.x * (double)wd.x + (double)xv.y * (double)wd.y;
    #pragma unroll
    for (int off = 32; off > 0; off >>= 1) {
        ap += __shfl_down(ap, off);
        aq += __shfl_down(aq, off);
    }
    if (lane == 0) { p[wave] = (float)ap; q[wave] = (float)aq; }
}

__global__ void score_kernel(const int* __restrict__ row, const int* __restrict__ col,
                             const float* __restrict__ p, const float* __restrict__ q,
                             const float* __restrict__ bptr, float* __restrict__ score,
                             unsigned int* __restrict__ node_max, int E) {
    int e = blockIdx.x * blockDim.x + threadIdx.x;
    if (e >= E) return;
    float s = p[row[e]] + q[col[e]] + bptr[0];
    score[e] = s;
    if (s > 0.0f) atomicMax(&node_max[row[e]], __float_as_uint(s));
}

__global__ void exp_kernel(const int* __restrict__ row, const float* __restrict__ score,
                           const unsigned int* __restrict__ node_max, float* __restrict__ norm,
                           double* __restrict__ denom, int E) {
    int e = blockIdx.x * blockDim.x + threadIdx.x;
    if (e >= E) return;
    int u = row[e];
    unsigned int mb = node_max[u];
    float s = score[e];
    float ev = 0.0f;
    if (mb != 0u && s > 0.0f) {
        float m = __uint_as_float(mb);
        ev = (float)exp((double)(s - m));   // double exp ~correctly rounded
        atomicAdd(&denom[u], (double)ev);   // order-independent (double accum)
    }
    norm[e] = ev;
}

__global__ void norm_kernel(const int* __restrict__ row, const float* __restrict__ score,
                            const unsigned int* __restrict__ node_max,
                            const double* __restrict__ denom, float* __restrict__ norm,
                            unsigned long long* __restrict__ key, int E) {
    int e = blockIdx.x * blockDim.x + threadIdx.x;
    if (e >= E) return;
    int u = row[e];
    unsigned int mb = node_max[u];
    float nv;
    if (mb != 0u) {
        float s = score[e];
        if (s > 0.0f) {
            float d = (float)denom[u];
            nv = norm[e] / d + 0.5f;        // exact f32 div + add, same as ref
        } else {
            nv = 0.0f;
        }
    } else {
        nv = score[e];                       // raw score for rows with no positive edge
    }
    norm[e] = nv;
    key[e] = make_key(nv, e);
}

// ---- CSR build: degree histogram, single-block scan, scatter ----
__global__ void deg_kernel(const int* __restrict__ row, const int* __restrict__ col,
                           int* __restrict__ deg, int E) {
    int e = blockIdx.x * blockDim.x + threadIdx.x;
    if (e >= E) return;
    int u = row[e], v = col[e];
    if (u == v) return;                     // self-loops excluded from matching graph
    atomicAdd(&deg[u], 1);
    atomicAdd(&deg[v], 1);
}

__global__ void __launch_bounds__(1024) scan_kernel(const int* __restrict__ deg,
                                                    int* __restrict__ offs,
                                                    int* __restrict__ cursor, int N) {
    __shared__ int buf[1024];
    __shared__ int running;
    if (threadIdx.x == 0) running = 0;
    __syncthreads();
    for (int base = 0; base < N; base += 1024) {
        int i = base + (int)threadIdx.x;
        int v = (i < N) ? deg[i] : 0;
        buf[threadIdx.x] = v;
        __syncthreads();
        for (int off = 1; off < 1024; off <<= 1) {
            int t = (threadIdx.x >= (unsigned)off) ? buf[threadIdx.x - off] : 0;
            __syncthreads();
            buf[threadIdx.x] += t;
            __syncthreads();
        }
        int r = running;                    // stable: last write was before a barrier
        if (i < N) {
            int excl = r + buf[threadIdx.x] - v;
            offs[i] = excl;
            cursor[i] = excl;
        }
        int tot = buf[1023];
        __syncthreads();
        if (threadIdx.x == 0) running = r + tot;
        __syncthreads();
    }
    if (threadIdx.x == 0) offs[N] = running;
}

__global__ void csr_kernel(const int* __restrict__ row, const int* __restrict__ col,
                           const unsigned long long* __restrict__ key, int* __restrict__ cursor,
                           int* __restrict__ adj_n, unsigned long long* __restrict__ adj_k, int E) {
    int e = blockIdx.x * blockDim.x + threadIdx.x;
    if (e >= E) return;
    int u = row[e], v = col[e];
    if (u == v) return;
    unsigned long long k = key[e];
    int pu = atomicAdd(&cursor[u], 1);
    adj_n[pu] = v; adj_k[pu] = k;
    int pv = atomicAdd(&cursor[v], 1);
    adj_n[pv] = u; adj_k[pv] = k;
}

// ---- Suitor matching (Manne-Bisseling): exact greedy matching for distinct
// weights, asynchronous, one dispatch, no barriers. ws[v] = best (smallest)
// proposal key at v; monotone decreasing => stale reads are stale-high => safe.
__global__ void suitor_kernel(const int* __restrict__ offs, const int* __restrict__ adj_n,
                              const unsigned long long* __restrict__ adj_k,
                              unsigned long long* __restrict__ ws,
                              const int* __restrict__ row, const int* __restrict__ col, int N) {
    int u = blockIdx.x * blockDim.x + threadIdx.x;
    if (u >= N) return;
    int cur = u;
    for (int guard = 0; guard < 1000000 && cur >= 0; ++guard) {
        int lo = offs[cur], hi = offs[cur + 1];
        unsigned long long best = ~0ULL;
        int bestv = -1;
        for (int i = lo; i < hi; ++i) {
            unsigned long long k = adj_k[i];
            if (k < best) {
                int v = adj_n[i];
                if (k < AL(&ws[v])) { best = k; bestv = v; }
            }
        }
        if (bestv < 0) break;               // no feasible proposal: cur stays unmatched
        unsigned long long old = atomicMin(&ws[bestv], best);
        if (old > best) {
            // accepted; take over the displaced proposer's work (exactly-one-worker:
            // atomicMin hands each displaced value to exactly one caller)
            if (old == ~0ULL) break;
            int e = (int)(old & 0xffffffffu);
            int a = row[e];
            cur = (a == bestv) ? col[e] : a;
        }
        // else: beaten concurrently (ws[bestv] already <= best) -> rescan same cur
    }
}

// matched pair <=> mutual proposal: ws[u] == key[e] == ws[v].
__global__ void extract_kernel(const int* __restrict__ row, const int* __restrict__ col,
                               const unsigned long long* __restrict__ key,
                               const float* __restrict__ norm,
                               const unsigned long long* __restrict__ ws,
                               int* __restrict__ cluster, int* __restrict__ partner,
                               float* __restrict__ s_rep, int E) {
    int e = blockIdx.x * blockDim.x + threadIdx.x;
    if (e >= E) return;
    int u = row[e], v = col[e];
    if (u == v) return;
    unsigned long long k = key[e];
    if (ws[u] == k && ws[v] == k) {
        cluster[v] = u;                    // v merged into rep u (ref: cluster[c_s]=r_s)
        partner[u] = v;
        s_rep[u]   = norm[e];
    }
}

__global__ void newx_kernel(const float* __restrict__ x, const int* __restrict__ cluster,
                            const int* __restrict__ partner, const float* __restrict__ s_rep,
                            float* __restrict__ out, float* __restrict__ out_cluster,
                            float* __restrict__ out_isrep, int N) {
    int t = blockIdx.x * blockDim.x + threadIdx.x;
    if (t >= N * (IN_CH / 4)) return;
    int n = t >> 5;            // IN_CH/4 == 32 float4 per node
    int c = (t & 31) * 4;
    int cl = cluster[n];
    if ((t & 31) == 0) {
        out_cluster[n] = (float)cl;
        out_isrep[n]   = (cl == n) ? 1.0f : 0.0f;
    }
    float4 o;
    int v = partner[n];
    if (cl != n) {
        o = make_float4(0.f, 0.f, 0.f, 0.f);              // merged-away node row
    } else if (v != n) {
        float s = s_rep[n];
        float4 xu = *(const float4*)(x + (size_t)n * IN_CH + c);
        float4 xv = *(const float4*)(x + (size_t)v * IN_CH + c);
        o.x = (xu.x + xv.x) * s + xv.x;
        o.y = (xu.y + xv.y) * s + xv.y;
        o.z = (xu.z + xv.z) * s + xv.z;
        o.w = (xu.w + xv.w) * s + xv.w;
    } else {
        o = *(const float4*)(x + (size_t)n * IN_CH + c);  // untouched node
    }
    ((float4*)out)[t] = o;
}

__global__ void edges_kernel(const int* __restrict__ row, const int* __restrict__ col,
                             const float* __restrict__ w, const int* __restrict__ cluster,
                             float* __restrict__ out_nrow, float* __restrict__ out_ncol,
                             float* __restrict__ out_valid, float* __restrict__ out_w, int E) {
    int e = blockIdx.x * blockDim.x + threadIdx.x;
    if (e >= E) return;
    int nr = cluster[row[e]];
    int nc = cluster[col[e]];
    out_nrow[e]  = (float)nr;
    out_ncol[e]  = (float)nc;
    out_valid[e] = (nr != nc) ? 1.0f : 0.0f;
    out_w[e]     = w[e];
}

extern "C" void kernel_launch(void* const* d_in, const int* in_sizes, int n_in_args,
                              void* d_out, int out_size, void* d_ws, size_t ws_size,
                              hipStream_t stream) {
    const float* x     = (const float*)d_in[0];
    const float* w_src = (const float*)d_in[1];
    const float* w_dst = (const float*)d_in[2];
    const float* bptr  = (const float*)d_in[3];
    const int*   ei    = (const int*)d_in[4];
    const float* ew    = (const float*)d_in[5];
    const int N = in_sizes[0] / IN_CH;
    const int E = in_sizes[5];
    const int* row = ei;
    const int* col = ei + E;

    char* wsb = (char*)d_ws;
    size_t off = 0;
    auto alloc = [&](size_t bytes) -> void* {
        off = (off + 255) & ~(size_t)255;
        void* ptr = wsb + off;
        off += bytes;
        return ptr;
    };
    float*              score    = (float*)alloc((size_t)E * 4);
    float*              norm     = (float*)alloc((size_t)E * 4);
    unsigned long long* key      = (unsigned long long*)alloc((size_t)E * 8);
    int*                adj_n    = (int*)alloc((size_t)2 * E * 4);
    unsigned long long* adj_k    = (unsigned long long*)alloc((size_t)2 * E * 8);
    unsigned int*       node_max = (unsigned int*)alloc((size_t)N * 4);
    double*             denom    = (double*)alloc((size_t)N * 8);
    unsigned long long* wsuit    = (unsigned long long*)alloc((size_t)N * 8);
    int*                deg      = (int*)alloc((size_t)N * 4);
    int*                offs     = (int*)alloc((size_t)(N + 1) * 4);
    int*                cursor   = (int*)alloc((size_t)N * 4);
    int*                cluster  = (int*)alloc((size_t)N * 4);
    int*                partner  = (int*)alloc((size_t)N * 4);
    float*              s_rep    = (float*)alloc((size_t)N * 4);
    float*              pbuf     = (float*)alloc((size_t)N * 4);
    float*              qbuf     = (float*)alloc((size_t)N * 4);

    // Output layout: new_x[N*128] | cluster[N] | is_rep[N] | new_row[E] | new_col[E] | edge_valid[E] | edge_weight[E]
    float* out       = (float*)d_out;
    float* o_newx    = out;
    float* o_cluster = out + (size_t)N * IN_CH;
    float* o_isrep   = o_cluster + N;
    float* o_nrow    = o_isrep + N;
    float* o_ncol    = o_nrow + E;
    float* o_valid   = o_ncol + E;
    float* o_w       = o_valid + E;

    const int T = 256;
    hipLaunchKernelGGL(init_kernel, dim3((N + T - 1) / T), dim3(T), 0, stream,
                       node_max, denom, wsuit, deg, cluster, partner, s_rep, N);
    hipLaunchKernelGGL(proj_kernel, dim3((N * 64 + T - 1) / T), dim3(T), 0, stream,
                       x, w_src, w_dst, pbuf, qbuf, N);
    hipLaunchKernelGGL(score_kernel, dim3((E + T - 1) / T), dim3(T), 0, stream,
                       row, col, pbuf, qbuf, bptr, score, node_max, E);
    hipLaunchKernelGGL(exp_kernel, dim3((E + T - 1) / T), dim3(T), 0, stream,
                       row, score, node_max, norm, denom, E);
    hipLaunchKernelGGL(norm_kernel, dim3((E + T - 1) / T), dim3(T), 0, stream,
                       row, score, node_max, denom, norm, key, E);

    hipLaunchKernelGGL(deg_kernel, dim3((E + T - 1) / T), dim3(T), 0, stream,
                       row, col, deg, E);
    hipLaunchKernelGGL(scan_kernel, dim3(1), dim3(1024), 0, stream, deg, offs, cursor, N);
    hipLaunchKernelGGL(csr_kernel, dim3((E + T - 1) / T), dim3(T), 0, stream,
                       row, col, key, cursor, adj_n, adj_k, E);
    hipLaunchKernelGGL(suitor_kernel, dim3((N + T - 1) / T), dim3(T), 0, stream,
                       offs, adj_n, adj_k, wsuit, row, col, N);
    hipLaunchKernelGGL(extract_kernel, dim3((E + T - 1) / T), dim3(T), 0, stream,
                       row, col, key, norm, wsuit, cluster, partner, s_rep, E);

    hipLaunchKernelGGL(newx_kernel, dim3((N * 32 + T - 1) / T), dim3(T), 0, stream,
                       x, cluster, partner, s_rep, o_newx, o_cluster, o_isrep, N);
    hipLaunchKernelGGL(edges_kernel, dim3((E + T - 1) / T), dim3(T), 0, stream,
                       row, col, ew, cluster, o_nrow, o_ncol, o_valid, o_w, E);
    (void)score; (void)ws_size; (void)out_size; (void)n_in_args;
}

// Round 5
// 494.566 us; speedup vs baseline: 10.8186x; 1.4840x over previous
//
#include <hip/hip_runtime.h>
#include <cmath>

#define IN_CH 128
#define AL(p) __hip_atomic_load((p), __ATOMIC_RELAXED, __HIP_MEMORY_SCOPE_AGENT)

// Monotone descending key: smaller key == higher norm; ties -> smaller edge idx
// (matches stable argsort of -norm). All keys distinct.
__device__ __forceinline__ unsigned long long make_key(float norm, int e) {
    unsigned int b = __float_as_uint(norm);
    unsigned int asc = (b & 0x80000000u) ? ~b : (b | 0x80000000u); // monotone-increasing map
    unsigned int desc = ~asc;
    return (((unsigned long long)desc) << 32) | (unsigned int)e;
}

__global__ void init_kernel(unsigned int* node_max, double* denom, unsigned long long* ws,
                            int* deg, int* cluster, int* partner, float* s_rep, int N) {
    int i = blockIdx.x * blockDim.x + threadIdx.x;
    if (i >= N) return;
    node_max[i] = 0u;          // bits of +0.0f; any positive score has bits > 0
    denom[i]    = 0.0;
    ws[i]       = ~0ULL;
    deg[i]      = 0;
    cluster[i]  = i;
    partner[i]  = i;
    s_rep[i]    = 1.0f;
}

// One wave per node: p[n] = dot(x[n], w_src), q[n] = dot(x[n], w_dst), double accum.
__global__ void proj_kernel(const float* __restrict__ x, const float* __restrict__ w_src,
                            const float* __restrict__ w_dst, float* __restrict__ p,
                            float* __restrict__ q, int N) {
    int wave = (blockIdx.x * blockDim.x + threadIdx.x) >> 6;
    int lane = threadIdx.x & 63;
    if (wave >= N) return;
    float2 xv = ((const float2*)(x + (size_t)wave * IN_CH))[lane];
    float2 ws = ((const float2*)w_src)[lane];
    float2 wd = ((const float2*)w_dst)[lane];
    double ap = (double)xv.x * (double)ws.x + (double)xv.y * (double)ws.y;
    double aq = (double)xv.x * (double)wd.x + (double)xv.y * (double)wd.y;
    #pragma unroll
    for (int off = 32; off > 0; off >>= 1) {
        ap += __shfl_down(ap, off);
        aq += __shfl_down(aq, off);
    }
    if (lane == 0) { p[wave] = (float)ap; q[wave] = (float)aq; }
}

// Fused: edge score + per-source max (softmax prep) + degree histogram (CSR prep).
__global__ void score_kernel(const int* __restrict__ row, const int* __restrict__ col,
                             const float* __restrict__ p, const float* __restrict__ q,
                             const float* __restrict__ bptr, float* __restrict__ score,
                             unsigned int* __restrict__ node_max, int* __restrict__ deg, int E) {
    int e = blockIdx.x * blockDim.x + threadIdx.x;
    if (e >= E) return;
    int u = row[e], v = col[e];
    float s = p[u] + q[v] + bptr[0];
    score[e] = s;
    if (s > 0.0f) atomicMax(&node_max[u], __float_as_uint(s));
    if (u != v) {
        atomicAdd(&deg[u], 1);
        atomicAdd(&deg[v], 1);
    }
}

__global__ void exp_kernel(const int* __restrict__ row, const float* __restrict__ score,
                           const unsigned int* __restrict__ node_max, float* __restrict__ norm,
                           double* __restrict__ denom, int E) {
    int e = blockIdx.x * blockDim.x + threadIdx.x;
    if (e >= E) return;
    int u = row[e];
    unsigned int mb = node_max[u];
    float s = score[e];
    float ev = 0.0f;
    if (mb != 0u && s > 0.0f) {
        float m = __uint_as_float(mb);
        ev = (float)exp((double)(s - m));   // double exp ~correctly rounded
        atomicAdd(&denom[u], (double)ev);   // order-independent (double accum)
    }
    norm[e] = ev;
}

__global__ void norm_kernel(const int* __restrict__ row, const float* __restrict__ score,
                            const unsigned int* __restrict__ node_max,
                            const double* __restrict__ denom, float* __restrict__ norm,
                            unsigned long long* __restrict__ key, int E) {
    int e = blockIdx.x * blockDim.x + threadIdx.x;
    if (e >= E) return;
    int u = row[e];
    unsigned int mb = node_max[u];
    float nv;
    if (mb != 0u) {
        float s = score[e];
        if (s > 0.0f) {
            float d = (float)denom[u];
            nv = norm[e] / d + 0.5f;        // exact f32 div + add, same as ref
        } else {
            nv = 0.0f;
        }
    } else {
        nv = score[e];                       // raw score for rows with no positive edge
    }
    norm[e] = nv;
    key[e] = make_key(nv, e);
}

// Single-block exclusive scan, shuffle-based (3 barriers per 1024-chunk).
__global__ void __launch_bounds__(1024) scan_kernel(const int* __restrict__ deg,
                                                    int* __restrict__ offs,
                                                    int* __restrict__ cursor, int N) {
    __shared__ int wtot[16];
    __shared__ int woff[16];
    __shared__ int running_s;
    __shared__ int ctot_s;
    int lane = threadIdx.x & 63;
    int wid  = threadIdx.x >> 6;
    if (threadIdx.x == 0) running_s = 0;
    __syncthreads();
    for (int base = 0; base < N; base += 1024) {
        int i = base + (int)threadIdx.x;
        int v = (i < N) ? deg[i] : 0;
        int incl = v;
        #pragma unroll
        for (int off = 1; off < 64; off <<= 1) {
            int t = __shfl_up(incl, off);
            if (lane >= off) incl += t;
        }
        if (lane == 63) wtot[wid] = incl;
        __syncthreads();
        if (wid == 0) {
            int t = (lane < 16) ? wtot[lane] : 0;
            int inc2 = t;
            #pragma unroll
            for (int off = 1; off < 16; off <<= 1) {
                int s = __shfl_up(inc2, off);
                if (lane >= off) inc2 += s;
            }
            if (lane < 16) woff[lane] = inc2 - t;
            if (lane == 15) ctot_s = inc2;
        }
        __syncthreads();
        if (i < N) {
            int excl = running_s + woff[wid] + (incl - v);
            offs[i] = excl;
            cursor[i] = excl;
        }
        __syncthreads();
        if (threadIdx.x == 0) running_s += ctot_s;
    }
    __syncthreads();
    if (threadIdx.x == 0) offs[N] = running_s;
}

__global__ void csr_kernel(const int* __restrict__ row, const int* __restrict__ col,
                           const unsigned long long* __restrict__ key, int* __restrict__ cursor,
                           int* __restrict__ adj_n, unsigned long long* __restrict__ adj_k, int E) {
    int e = blockIdx.x * blockDim.x + threadIdx.x;
    if (e >= E) return;
    int u = row[e], v = col[e];
    if (u == v) return;
    unsigned long long k = key[e];
    int pu = atomicAdd(&cursor[u], 1);
    adj_n[pu] = v; adj_k[pu] = k;
    int pv = atomicAdd(&cursor[v], 1);
    adj_n[pv] = u; adj_k[pv] = k;
}

// ---- Suitor matching (Manne-Bisseling), wave-per-node. Exact greedy matching
// for distinct keys. ws[v] monotone-decreasing => stale reads are stale-high =>
// no false-infeasible, failures just retry. Whole wave follows displacement chains.
__global__ void suitor_kernel(const int* __restrict__ offs, const int* __restrict__ adj_n,
                              const unsigned long long* __restrict__ adj_k,
                              unsigned long long* __restrict__ ws,
                              const int* __restrict__ row, const int* __restrict__ col, int N) {
    int wave = (blockIdx.x * blockDim.x + threadIdx.x) >> 6;
    int lane = threadIdx.x & 63;
    if (wave >= N) return;
    int cur = wave;
    for (int guard = 0; guard < 1000000; ++guard) {
        int lo = offs[cur], hi = offs[cur + 1];
        unsigned long long bk = ~0ULL;
        int bv = -1;
        for (int i = lo + lane; i < hi; i += 64) {
            unsigned long long k = adj_k[i];
            if (k < bk) {
                int v = adj_n[i];
                if (k < AL(&ws[v])) { bk = k; bv = v; }
            }
        }
        // all-lanes butterfly min-reduce with payload
        #pragma unroll
        for (int off = 32; off > 0; off >>= 1) {
            unsigned long long ok = __shfl_xor(bk, off);
            int ov = __shfl_xor(bv, off);
            if (ok < bk) { bk = ok; bv = ov; }
        }
        if (bk == ~0ULL) break;             // no feasible proposal: cur stays unmatched
        unsigned long long old;
        if (lane == 0) old = atomicMin(&ws[bv], bk);
        old = __shfl(old, 0);
        if (old > bk) {
            // accepted; take over the displaced proposer (atomicMin hands each
            // displaced value to exactly one wave)
            if (old == ~0ULL) break;
            int e = (int)(old & 0xffffffffu);
            int a = row[e];                 // same address across lanes -> broadcast
            int b = col[e];
            cur = (a == bv) ? b : a;
        }
        // else: beaten concurrently (ws[bv] already <= bk) -> rescan same cur
    }
}

// matched pair <=> mutual proposal: ws[u] == key[e] == ws[v].
__global__ void extract_kernel(const int* __restrict__ row, const int* __restrict__ col,
                               const unsigned long long* __restrict__ key,
                               const float* __restrict__ norm,
                               const unsigned long long* __restrict__ ws,
                               int* __restrict__ cluster, int* __restrict__ partner,
                               float* __restrict__ s_rep, int E) {
    int e = blockIdx.x * blockDim.x + threadIdx.x;
    if (e >= E) return;
    int u = row[e], v = col[e];
    if (u == v) return;
    unsigned long long k = key[e];
    if (ws[u] == k && ws[v] == k) {
        cluster[v] = u;                    // v merged into rep u (ref: cluster[c_s]=r_s)
        partner[u] = v;
        s_rep[u]   = norm[e];
    }
}

__global__ void newx_kernel(const float* __restrict__ x, const int* __restrict__ cluster,
                            const int* __restrict__ partner, const float* __restrict__ s_rep,
                            float* __restrict__ out, float* __restrict__ out_cluster,
                            float* __restrict__ out_isrep, int N) {
    int t = blockIdx.x * blockDim.x + threadIdx.x;
    if (t >= N * (IN_CH / 4)) return;
    int n = t >> 5;            // IN_CH/4 == 32 float4 per node
    int c = (t & 31) * 4;
    int cl = cluster[n];
    if ((t & 31) == 0) {
        out_cluster[n] = (float)cl;
        out_isrep[n]   = (cl == n) ? 1.0f : 0.0f;
    }
    float4 o;
    int v = partner[n];
    if (cl != n) {
        o = make_float4(0.f, 0.f, 0.f, 0.f);              // merged-away node row
    } else if (v != n) {
        float s = s_rep[n];
        float4 xu = *(const float4*)(x + (size_t)n * IN_CH + c);
        float4 xv = *(const float4*)(x + (size_t)v * IN_CH + c);
        o.x = (xu.x + xv.x) * s + xv.x;
        o.y = (xu.y + xv.y) * s + xv.y;
        o.z = (xu.z + xv.z) * s + xv.z;
        o.w = (xu.w + xv.w) * s + xv.w;
    } else {
        o = *(const float4*)(x + (size_t)n * IN_CH + c);  // untouched node
    }
    ((float4*)out)[t] = o;
}

__global__ void edges_kernel(const int* __restrict__ row, const int* __restrict__ col,
                             const float* __restrict__ w, const int* __restrict__ cluster,
                             float* __restrict__ out_nrow, float* __restrict__ out_ncol,
                             float* __restrict__ out_valid, float* __restrict__ out_w, int E) {
    int e = blockIdx.x * blockDim.x + threadIdx.x;
    if (e >= E) return;
    int nr = cluster[row[e]];
    int nc = cluster[col[e]];
    out_nrow[e]  = (float)nr;
    out_ncol[e]  = (float)nc;
    out_valid[e] = (nr != nc) ? 1.0f : 0.0f;
    out_w[e]     = w[e];
}

extern "C" void kernel_launch(void* const* d_in, const int* in_sizes, int n_in_args,
                              void* d_out, int out_size, void* d_ws, size_t ws_size,
                              hipStream_t stream) {
    const float* x     = (const float*)d_in[0];
    const float* w_src = (const float*)d_in[1];
    const float* w_dst = (const float*)d_in[2];
    const float* bptr  = (const float*)d_in[3];
    const int*   ei    = (const int*)d_in[4];
    const float* ew    = (const float*)d_in[5];
    const int N = in_sizes[0] / IN_CH;
    const int E = in_sizes[5];
    const int* row = ei;
    const int* col = ei + E;

    char* wsb = (char*)d_ws;
    size_t off = 0;
    auto alloc = [&](size_t bytes) -> void* {
        off = (off + 255) & ~(size_t)255;
        void* ptr = wsb + off;
        off += bytes;
        return ptr;
    };
    float*              score    = (float*)alloc((size_t)E * 4);
    float*              norm     = (float*)alloc((size_t)E * 4);
    unsigned long long* key      = (unsigned long long*)alloc((size_t)E * 8);
    int*                adj_n    = (int*)alloc((size_t)2 * E * 4);
    unsigned long long* adj_k    = (unsigned long long*)alloc((size_t)2 * E * 8);
    unsigned int*       node_max = (unsigned int*)alloc((size_t)N * 4);
    double*             denom    = (double*)alloc((size_t)N * 8);
    unsigned long long* wsuit    = (unsigned long long*)alloc((size_t)N * 8);
    int*                deg      = (int*)alloc((size_t)N * 4);
    int*                offs     = (int*)alloc((size_t)(N + 1) * 4);
    int*                cursor   = (int*)alloc((size_t)N * 4);
    int*                cluster  = (int*)alloc((size_t)N * 4);
    int*                partner  = (int*)alloc((size_t)N * 4);
    float*              s_rep    = (float*)alloc((size_t)N * 4);
    float*              pbuf     = (float*)alloc((size_t)N * 4);
    float*              qbuf     = (float*)alloc((size_t)N * 4);

    // Output layout: new_x[N*128] | cluster[N] | is_rep[N] | new_row[E] | new_col[E] | edge_valid[E] | edge_weight[E]
    float* out       = (float*)d_out;
    float* o_newx    = out;
    float* o_cluster = out + (size_t)N * IN_CH;
    float* o_isrep   = o_cluster + N;
    float* o_nrow    = o_isrep + N;
    float* o_ncol    = o_nrow + E;
    float* o_valid   = o_ncol + E;
    float* o_w       = o_valid + E;

    const int T = 256;
    hipLaunchKernelGGL(init_kernel, dim3((N + T - 1) / T), dim3(T), 0, stream,
                       node_max, denom, wsuit, deg, cluster, partner, s_rep, N);
    hipLaunchKernelGGL(proj_kernel, dim3((N * 64 + T - 1) / T), dim3(T), 0, stream,
                       x, w_src, w_dst, pbuf, qbuf, N);
    hipLaunchKernelGGL(score_kernel, dim3((E + T - 1) / T), dim3(T), 0, stream,
                       row, col, pbuf, qbuf, bptr, score, node_max, deg, E);
    hipLaunchKernelGGL(exp_kernel, dim3((E + T - 1) / T), dim3(T), 0, stream,
                       row, score, node_max, norm, denom, E);
    hipLaunchKernelGGL(norm_kernel, dim3((E + T - 1) / T), dim3(T), 0, stream,
                       row, score, node_max, denom, norm, key, E);

    hipLaunchKernelGGL(scan_kernel, dim3(1), dim3(1024), 0, stream, deg, offs, cursor, N);
    hipLaunchKernelGGL(csr_kernel, dim3((E + T - 1) / T), dim3(T), 0, stream,
                       row, col, key, cursor, adj_n, adj_k, E);
    hipLaunchKernelGGL(suitor_kernel, dim3((N * 64 + T - 1) / T), dim3(T), 0, stream,
                       offs, adj_n, adj_k, wsuit, row, col, N);
    hipLaunchKernelGGL(extract_kernel, dim3((E + T - 1) / T), dim3(T), 0, stream,
                       row, col, key, norm, wsuit, cluster, partner, s_rep, E);

    hipLaunchKernelGGL(newx_kernel, dim3((N * 32 + T - 1) / T), dim3(T), 0, stream,
                       x, cluster, partner, s_rep, o_newx, o_cluster, o_isrep, N);
    hipLaunchKernelGGL(edges_kernel, dim3((E + T - 1) / T), dim3(T), 0, stream,
                       row, col, ew, cluster, o_nrow, o_ncol, o_valid, o_w, E);
    (void)score; (void)ws_size; (void)out_size; (void)n_in_args;
}

// Round 6
// 490.525 us; speedup vs baseline: 10.9078x; 1.0082x over previous
//
#include <hip/hip_runtime.h>
#include <cmath>

#define IN_CH 128
#define AL(p) __hip_atomic_load((p), __ATOMIC_RELAXED, __HIP_MEMORY_SCOPE_AGENT)

// Monotone descending key: smaller key == higher norm; ties -> smaller edge idx
// (matches stable argsort of -norm). All keys distinct. Low 32 bits = edge idx.
__device__ __forceinline__ unsigned long long make_key(float norm, int e) {
    unsigned int b = __float_as_uint(norm);
    unsigned int asc = (b & 0x80000000u) ? ~b : (b | 0x80000000u); // monotone-increasing map
    unsigned int desc = ~asc;
    return (((unsigned long long)desc) << 32) | (unsigned int)e;
}

// One wave per node: p[n] = dot(x[n], w_src), q[n] = dot(x[n], w_dst), double accum.
// Per-node state init folded in (gtid < N lanes).
__global__ void proj_kernel(const float* __restrict__ x, const float* __restrict__ w_src,
                            const float* __restrict__ w_dst, float* __restrict__ p,
                            float* __restrict__ q,
                            unsigned int* __restrict__ node_max, double* __restrict__ denom,
                            unsigned long long* __restrict__ wsuit, int* __restrict__ deg,
                            int* __restrict__ cluster, int* __restrict__ partner,
                            float* __restrict__ s_rep, int N) {
    int gtid = blockIdx.x * blockDim.x + threadIdx.x;
    if (gtid < N) {
        node_max[gtid] = 0u;       // bits of +0.0f; any positive score has bits > 0
        denom[gtid]    = 0.0;
        wsuit[gtid]    = ~0ULL;
        deg[gtid]      = 0;
        cluster[gtid]  = gtid;
        partner[gtid]  = gtid;
        s_rep[gtid]    = 1.0f;
    }
    int wave = gtid >> 6;
    int lane = threadIdx.x & 63;
    if (wave >= N) return;
    float2 xv = ((const float2*)(x + (size_t)wave * IN_CH))[lane];
    float2 ws = ((const float2*)w_src)[lane];
    float2 wd = ((const float2*)w_dst)[lane];
    double ap = (double)xv.x * (double)ws.x + (double)xv.y * (double)ws.y;
    double aq = (double)xv.x * (double)wd.x + (double)xv.y * (double)wd.y;
    #pragma unroll
    for (int off = 32; off > 0; off >>= 1) {
        ap += __shfl_down(ap, off);
        aq += __shfl_down(aq, off);
    }
    if (lane == 0) { p[wave] = (float)ap; q[wave] = (float)aq; }
}

// Fused: edge score + per-source max (softmax prep) + degree histogram + packed
// (row,col) build for the suitor phase.
__global__ void score_kernel(const int* __restrict__ row, const int* __restrict__ col,
                             const float* __restrict__ p, const float* __restrict__ q,
                             const float* __restrict__ bptr, float* __restrict__ score,
                             unsigned int* __restrict__ node_max, int* __restrict__ deg,
                             int2* __restrict__ rc, int E) {
    int e = blockIdx.x * blockDim.x + threadIdx.x;
    if (e >= E) return;
    int u = row[e], v = col[e];
    rc[e] = make_int2(u, v);
    float s = p[u] + q[v] + bptr[0];
    score[e] = s;
    if (s > 0.0f) atomicMax(&node_max[u], __float_as_uint(s));
    if (u != v) {
        atomicAdd(&deg[u], 1);
        atomicAdd(&deg[v], 1);
    }
}

__global__ void exp_kernel(const int* __restrict__ row, const float* __restrict__ score,
                           const unsigned int* __restrict__ node_max, float* __restrict__ norm,
                           double* __restrict__ denom, int E) {
    int e = blockIdx.x * blockDim.x + threadIdx.x;
    if (e >= E) return;
    int u = row[e];
    unsigned int mb = node_max[u];
    float s = score[e];
    float ev = 0.0f;
    if (mb != 0u && s > 0.0f) {
        float m = __uint_as_float(mb);
        ev = (float)exp((double)(s - m));   // double exp ~correctly rounded
        atomicAdd(&denom[u], (double)ev);   // order-independent (double accum)
    }
    norm[e] = ev;
}

// Single-block exclusive scan, shuffle-based.
__global__ void __launch_bounds__(1024) scan_kernel(const int* __restrict__ deg,
                                                    int* __restrict__ offs,
                                                    int* __restrict__ cursor, int N) {
    __shared__ int wtot[16];
    __shared__ int woff[16];
    __shared__ int running_s;
    __shared__ int ctot_s;
    int lane = threadIdx.x & 63;
    int wid  = threadIdx.x >> 6;
    if (threadIdx.x == 0) running_s = 0;
    __syncthreads();
    for (int base = 0; base < N; base += 1024) {
        int i = base + (int)threadIdx.x;
        int v = (i < N) ? deg[i] : 0;
        int incl = v;
        #pragma unroll
        for (int off = 1; off < 64; off <<= 1) {
            int t = __shfl_up(incl, off);
            if (lane >= off) incl += t;
        }
        if (lane == 63) wtot[wid] = incl;
        __syncthreads();
        if (wid == 0) {
            int t = (lane < 16) ? wtot[lane] : 0;
            int inc2 = t;
            #pragma unroll
            for (int off = 1; off < 16; off <<= 1) {
                int s = __shfl_up(inc2, off);
                if (lane >= off) inc2 += s;
            }
            if (lane < 16) woff[lane] = inc2 - t;
            if (lane == 15) ctot_s = inc2;
        }
        __syncthreads();
        if (i < N) {
            int excl = running_s + woff[wid] + (incl - v);
            offs[i] = excl;
            cursor[i] = excl;
        }
        __syncthreads();
        if (threadIdx.x == 0) running_s += ctot_s;
    }
    __syncthreads();
    if (threadIdx.x == 0) offs[N] = running_s;
}

// Fused: finalize norm (exact f32 div + 0.5, same as ref) + key + CSR scatter.
// Adjacency stores ONLY the key (8B); neighbor derived from rc[key&0xffffffff].
__global__ void norm_csr_kernel(const int* __restrict__ row, const int* __restrict__ col,
                                const float* __restrict__ score,
                                const unsigned int* __restrict__ node_max,
                                const double* __restrict__ denom, float* __restrict__ norm,
                                int* __restrict__ cursor, unsigned long long* __restrict__ adj_k,
                                int E) {
    int e = blockIdx.x * blockDim.x + threadIdx.x;
    if (e >= E) return;
    int u = row[e], v = col[e];
    unsigned int mb = node_max[u];
    float nv;
    if (mb != 0u) {
        float s = score[e];
        if (s > 0.0f) {
            float d = (float)denom[u];
            nv = norm[e] / d + 0.5f;        // exact f32 div + add, same as ref
        } else {
            nv = 0.0f;
        }
    } else {
        nv = score[e];                       // raw score for rows with no positive edge
    }
    norm[e] = nv;
    if (u != v) {
        unsigned long long k = make_key(nv, e);
        int pu = atomicAdd(&cursor[u], 1);
        adj_k[pu] = k;
        int pv = atomicAdd(&cursor[v], 1);
        adj_k[pv] = k;
    }
}

// ---- Suitor matching (Manne-Bisseling), wave-per-node. Exact greedy matching
// for distinct keys. ws[v] monotone-decreasing => stale reads are stale-high =>
// no false-infeasible, failures just retry. Whole wave follows displacement chains.
__global__ void suitor_kernel(const int* __restrict__ offs,
                              const unsigned long long* __restrict__ adj_k,
                              const int2* __restrict__ rc,
                              unsigned long long* __restrict__ ws, int N) {
    int wave = (blockIdx.x * blockDim.x + threadIdx.x) >> 6;
    int lane = threadIdx.x & 63;
    if (wave >= N) return;
    int cur = wave;
    for (int guard = 0; guard < 1000000; ++guard) {
        int lo = offs[cur], hi = offs[cur + 1];
        unsigned long long bk = ~0ULL;
        int bv = -1;
        for (int i = lo + lane; i < hi; i += 64) {
            unsigned long long k = adj_k[i];
            if (k < bk) {
                int e = (int)(k & 0xffffffffu);
                int2 pr = rc[e];
                int v = pr.x ^ pr.y ^ cur;  // other endpoint (cur is one of pr.x/pr.y)
                if (k < AL(&ws[v])) { bk = k; bv = v; }
            }
        }
        // all-lanes butterfly min-reduce with payload
        #pragma unroll
        for (int off = 32; off > 0; off >>= 1) {
            unsigned long long ok = __shfl_xor(bk, off);
            int ov = __shfl_xor(bv, off);
            if (ok < bk) { bk = ok; bv = ov; }
        }
        if (bk == ~0ULL) break;             // no feasible proposal: cur stays unmatched
        unsigned long long old;
        if (lane == 0) old = atomicMin(&ws[bv], bk);
        old = __shfl(old, 0);
        if (old > bk) {
            // accepted; take over the displaced proposer (atomicMin hands each
            // displaced value to exactly one wave)
            if (old == ~0ULL) break;
            int e = (int)(old & 0xffffffffu);
            int2 pr = rc[e];                // same address across lanes -> broadcast
            cur = pr.x ^ pr.y ^ bv;         // displaced proposer = other endpoint of e
        }
        // else: beaten concurrently (ws[bv] already <= bk) -> rescan same cur
    }
}

// matched pair <=> mutual proposal: ws[u] == key(e) == ws[v]. Key recomputed
// (pure function of norm[e], e).
__global__ void extract_kernel(const int* __restrict__ row, const int* __restrict__ col,
                               const float* __restrict__ norm,
                               const unsigned long long* __restrict__ ws,
                               int* __restrict__ cluster, int* __restrict__ partner,
                               float* __restrict__ s_rep, int E) {
    int e = blockIdx.x * blockDim.x + threadIdx.x;
    if (e >= E) return;
    int u = row[e], v = col[e];
    if (u == v) return;
    float nv = norm[e];
    unsigned long long k = make_key(nv, e);
    if (ws[u] == k && ws[v] == k) {
        cluster[v] = u;                    // v merged into rep u (ref: cluster[c_s]=r_s)
        partner[u] = v;
        s_rep[u]   = nv;
    }
}

__global__ void newx_kernel(const float* __restrict__ x, const int* __restrict__ cluster,
                            const int* __restrict__ partner, const float* __restrict__ s_rep,
                            float* __restrict__ out, float* __restrict__ out_cluster,
                            float* __restrict__ out_isrep, int N) {
    int t = blockIdx.x * blockDim.x + threadIdx.x;
    if (t >= N * (IN_CH / 4)) return;
    int n = t >> 5;            // IN_CH/4 == 32 float4 per node
    int c = (t & 31) * 4;
    int cl = cluster[n];
    if ((t & 31) == 0) {
        out_cluster[n] = (float)cl;
        out_isrep[n]   = (cl == n) ? 1.0f : 0.0f;
    }
    float4 o;
    int v = partner[n];
    if (cl != n) {
        o = make_float4(0.f, 0.f, 0.f, 0.f);              // merged-away node row
    } else if (v != n) {
        float s = s_rep[n];
        float4 xu = *(const float4*)(x + (size_t)n * IN_CH + c);
        float4 xv = *(const float4*)(x + (size_t)v * IN_CH + c);
        o.x = (xu.x + xv.x) * s + xv.x;
        o.y = (xu.y + xv.y) * s + xv.y;
        o.z = (xu.z + xv.z) * s + xv.z;
        o.w = (xu.w + xv.w) * s + xv.w;
    } else {
        o = *(const float4*)(x + (size_t)n * IN_CH + c);  // untouched node
    }
    ((float4*)out)[t] = o;
}

__global__ void edges_kernel(const int* __restrict__ row, const int* __restrict__ col,
                             const float* __restrict__ w, const int* __restrict__ cluster,
                             float* __restrict__ out_nrow, float* __restrict__ out_ncol,
                             float* __restrict__ out_valid, float* __restrict__ out_w, int E) {
    int e = blockIdx.x * blockDim.x + threadIdx.x;
    if (e >= E) return;
    int nr = cluster[row[e]];
    int nc = cluster[col[e]];
    out_nrow[e]  = (float)nr;
    out_ncol[e]  = (float)nc;
    out_valid[e] = (nr != nc) ? 1.0f : 0.0f;
    out_w[e]     = w[e];
}

extern "C" void kernel_launch(void* const* d_in, const int* in_sizes, int n_in_args,
                              void* d_out, int out_size, void* d_ws, size_t ws_size,
                              hipStream_t stream) {
    const float* x     = (const float*)d_in[0];
    const float* w_src = (const float*)d_in[1];
    const float* w_dst = (const float*)d_in[2];
    const float* bptr  = (const float*)d_in[3];
    const int*   ei    = (const int*)d_in[4];
    const float* ew    = (const float*)d_in[5];
    const int N = in_sizes[0] / IN_CH;
    const int E = in_sizes[5];
    const int* row = ei;
    const int* col = ei + E;

    char* wsb = (char*)d_ws;
    size_t off = 0;
    auto alloc = [&](size_t bytes) -> void* {
        off = (off + 255) & ~(size_t)255;
        void* ptr = wsb + off;
        off += bytes;
        return ptr;
    };
    float*              score    = (float*)alloc((size_t)E * 4);
    float*              norm     = (float*)alloc((size_t)E * 4);
    int2*               rc       = (int2*)alloc((size_t)E * 8);
    unsigned long long* adj_k    = (unsigned long long*)alloc((size_t)2 * E * 8);
    unsigned int*       node_max = (unsigned int*)alloc((size_t)N * 4);
    double*             denom    = (double*)alloc((size_t)N * 8);
    unsigned long long* wsuit    = (unsigned long long*)alloc((size_t)N * 8);
    int*                deg      = (int*)alloc((size_t)N * 4);
    int*                offs     = (int*)alloc((size_t)(N + 1) * 4);
    int*                cursor   = (int*)alloc((size_t)N * 4);
    int*                cluster  = (int*)alloc((size_t)N * 4);
    int*                partner  = (int*)alloc((size_t)N * 4);
    float*              s_rep    = (float*)alloc((size_t)N * 4);
    float*              pbuf     = (float*)alloc((size_t)N * 4);
    float*              qbuf     = (float*)alloc((size_t)N * 4);

    // Output layout: new_x[N*128] | cluster[N] | is_rep[N] | new_row[E] | new_col[E] | edge_valid[E] | edge_weight[E]
    float* out       = (float*)d_out;
    float* o_newx    = out;
    float* o_cluster = out + (size_t)N * IN_CH;
    float* o_isrep   = o_cluster + N;
    float* o_nrow    = o_isrep + N;
    float* o_ncol    = o_nrow + E;
    float* o_valid   = o_ncol + E;
    float* o_w       = o_valid + E;

    const int T = 256;
    hipLaunchKernelGGL(proj_kernel, dim3((N * 64 + T - 1) / T), dim3(T), 0, stream,
                       x, w_src, w_dst, pbuf, qbuf,
                       node_max, denom, wsuit, deg, cluster, partner, s_rep, N);
    hipLaunchKernelGGL(score_kernel, dim3((E + T - 1) / T), dim3(T), 0, stream,
                       row, col, pbuf, qbuf, bptr, score, node_max, deg, rc, E);
    hipLaunchKernelGGL(exp_kernel, dim3((E + T - 1) / T), dim3(T), 0, stream,
                       row, score, node_max, norm, denom, E);
    hipLaunchKernelGGL(scan_kernel, dim3(1), dim3(1024), 0, stream, deg, offs, cursor, N);
    hipLaunchKernelGGL(norm_csr_kernel, dim3((E + T - 1) / T), dim3(T), 0, stream,
                       row, col, score, node_max, denom, norm, cursor, adj_k, E);
    hipLaunchKernelGGL(suitor_kernel, dim3((N * 64 + T - 1) / T), dim3(T), 0, stream,
                       offs, adj_k, rc, wsuit, N);
    hipLaunchKernelGGL(extract_kernel, dim3((E + T - 1) / T), dim3(T), 0, stream,
                       row, col, norm, wsuit, cluster, partner, s_rep, E);
    hipLaunchKernelGGL(newx_kernel, dim3((N * 32 + T - 1) / T), dim3(T), 0, stream,
                       x, cluster, partner, s_rep, o_newx, o_cluster, o_isrep, N);
    hipLaunchKernelGGL(edges_kernel, dim3((E + T - 1) / T), dim3(T), 0, stream,
                       row, col, ew, cluster, o_nrow, o_ncol, o_valid, o_w, E);
    (void)ws_size; (void)out_size; (void)n_in_args;
}

// Round 7
// 419.399 us; speedup vs baseline: 12.7576x; 1.1696x over previous
//
#include <hip/hip_runtime.h>
#include <cmath>

#define IN_CH 128
#define AL(p) __hip_atomic_load((p), __ATOMIC_RELAXED, __HIP_MEMORY_SCOPE_AGENT)

// Monotone descending key: smaller key == higher norm; ties -> smaller edge idx
// (matches stable argsort of -norm). All keys distinct. Low 32 bits = edge idx.
__device__ __forceinline__ unsigned long long make_key(float norm, int e) {
    unsigned int b = __float_as_uint(norm);
    unsigned int asc = (b & 0x80000000u) ? ~b : (b | 0x80000000u); // monotone-increasing map
    unsigned int desc = ~asc;
    return (((unsigned long long)desc) << 32) | (unsigned int)e;
}

// One wave per node: p[n] = dot(x[n], w_src), q[n] = dot(x[n], w_dst), double accum.
// Per-node state init folded in.
__global__ void proj_kernel(const float* __restrict__ x, const float* __restrict__ w_src,
                            const float* __restrict__ w_dst, float* __restrict__ p,
                            float* __restrict__ q,
                            unsigned int* __restrict__ node_max, double* __restrict__ denom,
                            unsigned long long* __restrict__ wsuit, int* __restrict__ deg,
                            int* __restrict__ cluster, int* __restrict__ partner,
                            float* __restrict__ s_rep, int* __restrict__ bump, int N) {
    int gtid = blockIdx.x * blockDim.x + threadIdx.x;
    if (gtid == 0) *bump = 0;
    if (gtid < N) {
        node_max[gtid] = 0u;       // bits of +0.0f; any positive score has bits > 0
        denom[gtid]    = 0.0;
        wsuit[gtid]    = ~0ULL;
        deg[gtid]      = 0;
        cluster[gtid]  = gtid;
        partner[gtid]  = gtid;
        s_rep[gtid]    = 1.0f;
    }
    int wave = gtid >> 6;
    int lane = threadIdx.x & 63;
    if (wave >= N) return;
    float2 xv = ((const float2*)(x + (size_t)wave * IN_CH))[lane];
    float2 ws = ((const float2*)w_src)[lane];
    float2 wd = ((const float2*)w_dst)[lane];
    double ap = (double)xv.x * (double)ws.x + (double)xv.y * (double)ws.y;
    double aq = (double)xv.x * (double)wd.x + (double)xv.y * (double)wd.y;
    #pragma unroll
    for (int off = 32; off > 0; off >>= 1) {
        ap += __shfl_down(ap, off);
        aq += __shfl_down(aq, off);
    }
    if (lane == 0) { p[wave] = (float)ap; q[wave] = (float)aq; }
}

// Fused: edge score + per-source max (softmax prep) + degree histogram + packed
// (row,col) for displacement chains.
__global__ void score_kernel(const int* __restrict__ row, const int* __restrict__ col,
                             const float* __restrict__ p, const float* __restrict__ q,
                             const float* __restrict__ bptr, float* __restrict__ score,
                             unsigned int* __restrict__ node_max, int* __restrict__ deg,
                             int2* __restrict__ rc, int E) {
    int e = blockIdx.x * blockDim.x + threadIdx.x;
    if (e >= E) return;
    int u = row[e], v = col[e];
    rc[e] = make_int2(u, v);
    float s = p[u] + q[v] + bptr[0];
    score[e] = s;
    if (s > 0.0f) atomicMax(&node_max[u], __float_as_uint(s));
    if (u != v) {
        atomicAdd(&deg[u], 1);
        atomicAdd(&deg[v], 1);
    }
}

// Fused: per-edge exp + denom accumulation; per-node CSR segment allocation
// (order-free: segments need only be disjoint, not node-ordered).
__global__ void exp_alloc_kernel(const int* __restrict__ row, const float* __restrict__ score,
                                 const unsigned int* __restrict__ node_max,
                                 float* __restrict__ norm, double* __restrict__ denom,
                                 const int* __restrict__ deg, int* __restrict__ bump,
                                 int2* __restrict__ seg, int* __restrict__ cursor,
                                 int E, int N) {
    int i = blockIdx.x * blockDim.x + threadIdx.x;
    if (i < N) {
        int d = deg[i];
        int lo = atomicAdd(bump, d);
        seg[i] = make_int2(lo, lo + d);
        cursor[i] = lo;
    }
    if (i >= E) return;
    int u = row[i];
    unsigned int mb = node_max[u];
    float s = score[i];
    float ev = 0.0f;
    if (mb != 0u && s > 0.0f) {
        float m = __uint_as_float(mb);
        ev = (float)exp((double)(s - m));   // double exp ~correctly rounded
        atomicAdd(&denom[u], (double)ev);   // order-independent (double accum)
    }
    norm[i] = ev;
}

// Fused: finalize norm (exact f32 div + 0.5, same as ref) + key + CSR scatter.
// Adjacency entry = 16B {key, neighbor}: ONE scattered store per endpoint,
// no dependent rc lookup in the suitor scan.
__global__ void norm_csr_kernel(const int* __restrict__ row, const int* __restrict__ col,
                                const float* __restrict__ score,
                                const unsigned int* __restrict__ node_max,
                                const double* __restrict__ denom, float* __restrict__ norm,
                                int* __restrict__ cursor, ulonglong2* __restrict__ adj,
                                int E) {
    int e = blockIdx.x * blockDim.x + threadIdx.x;
    if (e >= E) return;
    int u = row[e], v = col[e];
    unsigned int mb = node_max[u];
    float nv;
    if (mb != 0u) {
        float s = score[e];
        if (s > 0.0f) {
            float d = (float)denom[u];
            nv = norm[e] / d + 0.5f;        // exact f32 div + add, same as ref
        } else {
            nv = 0.0f;
        }
    } else {
        nv = score[e];                       // raw score for rows with no positive edge
    }
    norm[e] = nv;
    if (u != v) {
        unsigned long long k = make_key(nv, e);
        int pu = atomicAdd(&cursor[u], 1);
        adj[pu] = make_ulonglong2(k, (unsigned long long)v);
        int pv = atomicAdd(&cursor[v], 1);
        adj[pv] = make_ulonglong2(k, (unsigned long long)u);
    }
}

// ---- Suitor matching (Manne-Bisseling), wave-per-node. Exact greedy matching
// for distinct keys. ws[v] monotone-decreasing => stale reads are stale-high =>
// no false-infeasible, failures just retry. Whole wave follows displacement chains.
__global__ void suitor_kernel(const int2* __restrict__ seg,
                              const ulonglong2* __restrict__ adj,
                              const int2* __restrict__ rc,
                              unsigned long long* __restrict__ ws, int N) {
    int wave = (blockIdx.x * blockDim.x + threadIdx.x) >> 6;
    int lane = threadIdx.x & 63;
    if (wave >= N) return;
    int cur = wave;
    for (int guard = 0; guard < 1000000; ++guard) {
        int2 lohi = seg[cur];
        unsigned long long bk = ~0ULL;
        int bv = -1;
        for (int i = lohi.x + lane; i < lohi.y; i += 64) {
            ulonglong2 ent = adj[i];        // coalesced 16B
            unsigned long long k = ent.x;
            if (k < bk) {
                int v = (int)ent.y;
                if (k < AL(&ws[v])) { bk = k; bv = v; }
            }
        }
        // all-lanes butterfly min-reduce with payload
        #pragma unroll
        for (int off = 32; off > 0; off >>= 1) {
            unsigned long long ok = __shfl_xor(bk, off);
            int ov = __shfl_xor(bv, off);
            if (ok < bk) { bk = ok; bv = ov; }
        }
        if (bk == ~0ULL) break;             // no feasible proposal: cur stays unmatched
        unsigned long long old;
        if (lane == 0) old = atomicMin(&ws[bv], bk);
        old = __shfl(old, 0);
        if (old > bk) {
            // accepted; take over the displaced proposer (atomicMin hands each
            // displaced value to exactly one wave)
            if (old == ~0ULL) break;
            int e = (int)(old & 0xffffffffu);
            int2 pr = rc[e];                // same address across lanes -> broadcast
            cur = pr.x ^ pr.y ^ bv;         // displaced proposer = other endpoint of e
        }
        // else: beaten concurrently (ws[bv] already <= bk) -> rescan same cur
    }
}

// matched pair <=> mutual proposal: ws[u] == key(e) == ws[v]. Key recomputed
// (pure function of norm[e], e).
__global__ void extract_kernel(const int* __restrict__ row, const int* __restrict__ col,
                               const float* __restrict__ norm,
                               const unsigned long long* __restrict__ ws,
                               int* __restrict__ cluster, int* __restrict__ partner,
                               float* __restrict__ s_rep, int E) {
    int e = blockIdx.x * blockDim.x + threadIdx.x;
    if (e >= E) return;
    int u = row[e], v = col[e];
    if (u == v) return;
    float nv = norm[e];
    unsigned long long k = make_key(nv, e);
    if (ws[u] == k && ws[v] == k) {
        cluster[v] = u;                    // v merged into rep u (ref: cluster[c_s]=r_s)
        partner[u] = v;
        s_rep[u]   = nv;
    }
}

// Fused epilogue: blocks [0, NB1) do new_x/cluster/is_rep; blocks [NB1, ..) do edges.
__global__ void out_kernel(const float* __restrict__ x, const int* __restrict__ cluster,
                           const int* __restrict__ partner, const float* __restrict__ s_rep,
                           const int* __restrict__ row, const int* __restrict__ col,
                           const float* __restrict__ w,
                           float* __restrict__ out_newx, float* __restrict__ out_cluster,
                           float* __restrict__ out_isrep, float* __restrict__ out_nrow,
                           float* __restrict__ out_ncol, float* __restrict__ out_valid,
                           float* __restrict__ out_w, int N, int E, int NB1) {
    if ((int)blockIdx.x < NB1) {
        int t = blockIdx.x * blockDim.x + threadIdx.x;
        if (t >= N * (IN_CH / 4)) return;
        int n = t >> 5;            // IN_CH/4 == 32 float4 per node
        int c = (t & 31) * 4;
        int cl = cluster[n];
        if ((t & 31) == 0) {
            out_cluster[n] = (float)cl;
            out_isrep[n]   = (cl == n) ? 1.0f : 0.0f;
        }
        float4 o;
        int v = partner[n];
        if (cl != n) {
            o = make_float4(0.f, 0.f, 0.f, 0.f);              // merged-away node row
        } else if (v != n) {
            float s = s_rep[n];
            float4 xu = *(const float4*)(x + (size_t)n * IN_CH + c);
            float4 xv = *(const float4*)(x + (size_t)v * IN_CH + c);
            o.x = (xu.x + xv.x) * s + xv.x;
            o.y = (xu.y + xv.y) * s + xv.y;
            o.z = (xu.z + xv.z) * s + xv.z;
            o.w = (xu.w + xv.w) * s + xv.w;
        } else {
            o = *(const float4*)(x + (size_t)n * IN_CH + c);  // untouched node
        }
        ((float4*)out_newx)[t] = o;
    } else {
        int e = (blockIdx.x - NB1) * blockDim.x + threadIdx.x;
        if (e >= E) return;
        int nr = cluster[row[e]];
        int nc = cluster[col[e]];
        out_nrow[e]  = (float)nr;
        out_ncol[e]  = (float)nc;
        out_valid[e] = (nr != nc) ? 1.0f : 0.0f;
        out_w[e]     = w[e];
    }
}

extern "C" void kernel_launch(void* const* d_in, const int* in_sizes, int n_in_args,
                              void* d_out, int out_size, void* d_ws, size_t ws_size,
                              hipStream_t stream) {
    const float* x     = (const float*)d_in[0];
    const float* w_src = (const float*)d_in[1];
    const float* w_dst = (const float*)d_in[2];
    const float* bptr  = (const float*)d_in[3];
    const int*   ei    = (const int*)d_in[4];
    const float* ew    = (const float*)d_in[5];
    const int N = in_sizes[0] / IN_CH;
    const int E = in_sizes[5];
    const int* row = ei;
    const int* col = ei + E;

    char* wsb = (char*)d_ws;
    size_t off = 0;
    auto alloc = [&](size_t bytes) -> void* {
        off = (off + 255) & ~(size_t)255;
        void* ptr = wsb + off;
        off += bytes;
        return ptr;
    };
    float*              score    = (float*)alloc((size_t)E * 4);
    float*              norm     = (float*)alloc((size_t)E * 4);
    int2*               rc       = (int2*)alloc((size_t)E * 8);
    ulonglong2*         adj      = (ulonglong2*)alloc((size_t)2 * E * 16);
    unsigned int*       node_max = (unsigned int*)alloc((size_t)N * 4);
    double*             denom    = (double*)alloc((size_t)N * 8);
    unsigned long long* wsuit    = (unsigned long long*)alloc((size_t)N * 8);
    int*                deg      = (int*)alloc((size_t)N * 4);
    int2*               seg      = (int2*)alloc((size_t)N * 8);
    int*                cursor   = (int*)alloc((size_t)N * 4);
    int*                cluster  = (int*)alloc((size_t)N * 4);
    int*                partner  = (int*)alloc((size_t)N * 4);
    float*              s_rep    = (float*)alloc((size_t)N * 4);
    float*              pbuf     = (float*)alloc((size_t)N * 4);
    float*              qbuf     = (float*)alloc((size_t)N * 4);
    int*                bump     = (int*)alloc(64);

    // Output layout: new_x[N*128] | cluster[N] | is_rep[N] | new_row[E] | new_col[E] | edge_valid[E] | edge_weight[E]
    float* out       = (float*)d_out;
    float* o_newx    = out;
    float* o_cluster = out + (size_t)N * IN_CH;
    float* o_isrep   = o_cluster + N;
    float* o_nrow    = o_isrep + N;
    float* o_ncol    = o_nrow + E;
    float* o_valid   = o_ncol + E;
    float* o_w       = o_valid + E;

    const int T = 256;
    hipLaunchKernelGGL(proj_kernel, dim3((N * 64 + T - 1) / T), dim3(T), 0, stream,
                       x, w_src, w_dst, pbuf, qbuf,
                       node_max, denom, wsuit, deg, cluster, partner, s_rep, bump, N);
    hipLaunchKernelGGL(score_kernel, dim3((E + T - 1) / T), dim3(T), 0, stream,
                       row, col, pbuf, qbuf, bptr, score, node_max, deg, rc, E);
    hipLaunchKernelGGL(exp_alloc_kernel, dim3((E + T - 1) / T), dim3(T), 0, stream,
                       row, score, node_max, norm, denom, deg, bump, seg, cursor, E, N);
    hipLaunchKernelGGL(norm_csr_kernel, dim3((E + T - 1) / T), dim3(T), 0, stream,
                       row, col, score, node_max, denom, norm, cursor, adj, E);
    hipLaunchKernelGGL(suitor_kernel, dim3((N * 64 + T - 1) / T), dim3(T), 0, stream,
                       seg, adj, rc, wsuit, N);
    hipLaunchKernelGGL(extract_kernel, dim3((E + T - 1) / T), dim3(T), 0, stream,
                       row, col, norm, wsuit, cluster, partner, s_rep, E);
    const int NB1 = (N * 32 + T - 1) / T;
    const int NB2 = (E + T - 1) / T;
    hipLaunchKernelGGL(out_kernel, dim3(NB1 + NB2), dim3(T), 0, stream,
                       x, cluster, partner, s_rep, row, col, ew,
                       o_newx, o_cluster, o_isrep, o_nrow, o_ncol, o_valid, o_w, N, E, NB1);
    (void)ws_size; (void)out_size; (void)n_in_args;
}